// Round 3
// baseline (2311.898 us; speedup 1.0000x reference)
//
#include <hip/hip_runtime.h>
#include <math.h>

#define Hh 128
#define Ww 128
#define HW (Hh*Ww)
#define Bn 4
#define Cn 64
#define On 64
#define CCH 8                 // channels per LDS chunk in dcn_k

// workspace layout (in floats)
#define OM_OFF   0                          // B*27*HW = 1,769,472 floats
#define CONV_OFF (Bn*27*HW)                 // B*64*HW = 4,194,304 floats
#define SS_OFF   (CONV_OFF + Bn*On*HW)      // 128 floats (scale[64], shift[64])
#define PART_OFF (SS_OFF + 128)             // 512 blocks * 128 floats partials

// ---------------------------------------------------------------------------
// Kernel A: offset-predicting 3x3 conv (C=64 -> 27), stride 1, pad 1.
// One thread per pixel, 27 accumulators (R0/R1 version — the 3-way split
// regressed by triplicating x reads).
// ---------------------------------------------------------------------------
__global__ __launch_bounds__(128) void offset_conv_k(
    const float* __restrict__ x, const float* __restrict__ ow,
    const float* __restrict__ ob, float* __restrict__ om)
{
    int bh = blockIdx.x;
    int b = bh >> 7;
    int h = bh & 127;
    int w = threadIdx.x;

    float acc[27];
#pragma unroll
    for (int o = 0; o < 27; ++o) acc[o] = ob[o];

    const float* xb = x + (size_t)b * Cn * HW;
    for (int c = 0; c < Cn; ++c) {
        const float* xp = xb + c * HW;
        float v[9];
#pragma unroll
        for (int ky = 0; ky < 3; ++ky) {
            int yy = h + ky - 1;
            int yc = min(max(yy, 0), Hh - 1);
            bool vy = (yy >= 0) && (yy < Hh);
#pragma unroll
            for (int kx = 0; kx < 3; ++kx) {
                int xx = w + kx - 1;
                int xc = min(max(xx, 0), Ww - 1);
                bool vx = (xx >= 0) && (xx < Ww);
                v[ky * 3 + kx] = (vy && vx) ? xp[yc * Ww + xc] : 0.0f;
            }
        }
        const float* wp = ow + c * 9;   // ow[o*576 + c*9 + t]
#pragma unroll
        for (int o = 0; o < 27; ++o) {
            const float* wo = wp + o * 576;
#pragma unroll
            for (int t = 0; t < 9; ++t) acc[o] += v[t] * wo[t];
        }
    }

    int p = h * Ww + w;
#pragma unroll
    for (int o = 0; o < 27; ++o) {
        float val = acc[o];
        if (o >= 18) val = 1.0f / (1.0f + __expf(-val));  // sigmoid for mask
        om[((size_t)b * 27 + o) * HW + p] = val;
    }
}

// ---------------------------------------------------------------------------
// Kernel B: deformable sampling + DCN conv, LDS-staged.
// Block = 256 threads = one row (b,h), all 64 output channels.
//   Prologue: 1152 (k,px) pairs -> owning thread computes 4 corner idx + 4
//             validity*mask-folded bilinear weights, held in registers.
//   Per C-chunk (8 ch): owners gather-sample into sL[8][9][128] (36 KB);
//             einsum threads (px, og) accumulate acc[32] from sL + uniform
//             (s_load) weights.
//   Epilogue: store conv, per-block stats partials (no atomics).
// ---------------------------------------------------------------------------
__global__ __launch_bounds__(256, 4) void dcn_k(
    const float* __restrict__ x, const float* __restrict__ om,
    const float* __restrict__ dw, float* __restrict__ conv,
    float* __restrict__ part)
{
    int b = blockIdx.x >> 7;
    int h = blockIdx.x & 127;
    int t = threadIdx.x;

    __shared__ float sL[CCH * 9 * 128];   // 36 KB

    // ---- prologue: per-(k,px) corner indices & folded weights in registers
    int   pidx[5][4];
    float pfw[5][4];
#pragma unroll
    for (int i = 0; i < 5; ++i) {
        int pid = t + 256 * i;
        bool ok = (pid < 1152);           // only i==4, t>=128 is invalid
        int k  = pid >> 7;
        int px = pid & 127;
        if (ok) {
            int p = h * Ww + px;
            const float* omb = om + (size_t)b * 27 * HW;
            float ox = omb[(size_t)k * HW + p];
            float oy = omb[(size_t)(9 + k) * HW + p];
            float m  = omb[(size_t)(18 + k) * HW + p];  // sigmoided already
            float py  = (float)(h - 1 + (k / 3)) + oy;
            float pxf = (float)(px - 1 + (k % 3)) + ox;
            float y0f = floorf(py), x0f = floorf(pxf);
            int y0 = (int)y0f, x0 = (int)x0f;
            float wy = py - y0f, wx = pxf - x0f;
#pragma unroll
            for (int dy = 0; dy < 2; ++dy) {
#pragma unroll
                for (int dx = 0; dx < 2; ++dx) {
                    int yi = y0 + dy, xi = x0 + dx;
                    bool valid = (yi >= 0) && (yi < Hh) && (xi >= 0) && (xi < Ww);
                    int yc = min(max(yi, 0), Hh - 1);
                    int xc = min(max(xi, 0), Ww - 1);
                    float wgt = (dy ? wy : 1.0f - wy) * (dx ? wx : 1.0f - wx);
                    pfw[i][dy * 2 + dx]  = valid ? (wgt * m) : 0.0f;
                    pidx[i][dy * 2 + dx] = yc * Ww + xc;
                }
            }
        } else {
#pragma unroll
            for (int j = 0; j < 4; ++j) { pfw[i][j] = 0.0f; pidx[i][j] = 0; }
        }
    }

    float acc[32];
#pragma unroll
    for (int j = 0; j < 32; ++j) acc[j] = 0.0f;

    int mypx = t & 127;
    int og   = t >> 7;                    // 0 or 1: outputs og*32 .. og*32+31

    for (int cc = 0; cc < Cn / CCH; ++cc) {
        // ---- sampling phase: fill sL for channels cc*8 .. cc*8+7
        const float* xbase = x + (size_t)(b * Cn + cc * CCH) * HW;
#pragma unroll
        for (int i = 0; i < 5; ++i) {
            int pid = t + 256 * i;
            if (pid < 1152) {
                int k  = pid >> 7;
                int px = pid & 127;
#pragma unroll
                for (int c2 = 0; c2 < CCH; ++c2) {
                    const float* xc = xbase + c2 * HW;
                    float v = pfw[i][0] * xc[pidx[i][0]]
                            + pfw[i][1] * xc[pidx[i][1]]
                            + pfw[i][2] * xc[pidx[i][2]]
                            + pfw[i][3] * xc[pidx[i][3]];
                    sL[(c2 * 9 + k) * 128 + px] = v;
                }
            }
        }
        __syncthreads();

        // ---- einsum phase: acc[j] += sL . w
        const float* wchunk = dw + (size_t)(og * 32) * 576 + cc * CCH * 9;
        for (int c2 = 0; c2 < CCH; ++c2) {
            float s[9];
#pragma unroll
            for (int k = 0; k < 9; ++k) s[k] = sL[(c2 * 9 + k) * 128 + mypx];
#pragma unroll
            for (int j = 0; j < 32; ++j) {
                const float* wo = wchunk + (size_t)j * 576 + c2 * 9;
#pragma unroll
                for (int k = 0; k < 9; ++k) acc[j] += s[k] * wo[k];
            }
        }
        __syncthreads();   // WAR: next chunk overwrites sL
    }

    // ---- store conv output
    float* cv = conv + ((size_t)b * On + og * 32) * HW + h * Ww + mypx;
#pragma unroll
    for (int j = 0; j < 32; ++j) cv[(size_t)j * HW] = acc[j];

    // ---- block stats partials: wave shuffle-reduce, combine via LDS
#pragma unroll
    for (int j = 0; j < 32; ++j) {
        float s1 = acc[j];
        float s2 = acc[j] * acc[j];
#pragma unroll
        for (int off = 32; off > 0; off >>= 1) {
            s1 += __shfl_down(s1, off, 64);
            s2 += __shfl_down(s2, off, 64);
        }
        if ((t & 63) == 0) {
            int wv = t >> 6;                      // wave 0..3 ; og = wv>>1
            sL[0 * 128 + wv * 32 + j] = s1;       // sums
            sL[512 + wv * 32 + j]     = s2;       // sumsq (disjoint region)
        }
    }
    __syncthreads();
    if (t < 128) {
        int stat = t >> 6;         // 0=sum, 1=sumsq
        int o    = t & 63;
        int og2  = o >> 5, j = o & 31;
        float v = sL[stat * 512 + (og2 * 2 + 0) * 32 + j]
                + sL[stat * 512 + (og2 * 2 + 1) * 32 + j];
        part[(size_t)blockIdx.x * 128 + t] = v;
    }
}

// ---------------------------------------------------------------------------
// Kernel C: reduce per-block partials -> BN scale/shift per channel
// ---------------------------------------------------------------------------
__global__ __launch_bounds__(128) void stats_k(
    const float* __restrict__ part, const float* __restrict__ gamma,
    const float* __restrict__ beta, float* __restrict__ ss)
{
    int t = threadIdx.x;           // stat = t>>6, o = t&63
    float a = 0.0f;
    for (int i = 0; i < Bn * Hh; ++i) a += part[(size_t)i * 128 + t];
    __shared__ float tmp[128];
    tmp[t] = a;
    __syncthreads();
    if (t < 64) {
        float n = (float)(Bn * HW);
        float mu = tmp[t] / n;
        float var = tmp[64 + t] / n - mu * mu;
        float sc = gamma[t] * rsqrtf(var + 1e-5f);
        ss[t] = sc;
        ss[64 + t] = beta[t] - mu * sc;
    }
}

// ---------------------------------------------------------------------------
// Kernel D: apply BN + ReLU, vectorized float4
// ---------------------------------------------------------------------------
__global__ __launch_bounds__(256) void bnrelu_k(
    const float* __restrict__ conv, const float* __restrict__ ss,
    float* __restrict__ out)
{
    int i = blockIdx.x * blockDim.x + threadIdx.x;   // float4 index
    int ch = (i >> 12) & 63;                         // HW/4 = 4096 float4/plane
    float sc = ss[ch];
    float sh = ss[64 + ch];
    const float4* cv = (const float4*)conv;
    float4* ov = (float4*)out;
    float4 v = cv[i];
    v.x = fmaxf(v.x * sc + sh, 0.0f);
    v.y = fmaxf(v.y * sc + sh, 0.0f);
    v.z = fmaxf(v.z * sc + sh, 0.0f);
    v.w = fmaxf(v.w * sc + sh, 0.0f);
    ov[i] = v;
}

// ---------------------------------------------------------------------------
extern "C" void kernel_launch(void* const* d_in, const int* in_sizes, int n_in,
                              void* d_out, int out_size, void* d_ws, size_t ws_size,
                              hipStream_t stream)
{
    const float* x     = (const float*)d_in[0];
    const float* ow    = (const float*)d_in[1];
    const float* ob    = (const float*)d_in[2];
    const float* dw    = (const float*)d_in[3];
    // d_in[4] = dcn_b: cancels exactly under BN mean subtraction -> unused
    const float* gamma = (const float*)d_in[5];
    const float* beta  = (const float*)d_in[6];

    float* ws    = (float*)d_ws;
    float* om    = ws + OM_OFF;
    float* conv  = ws + CONV_OFF;
    float* ss    = ws + SS_OFF;
    float* part  = ws + PART_OFF;

    offset_conv_k<<<dim3(Bn * Hh), dim3(128), 0, stream>>>(x, ow, ob, om);
    dcn_k<<<dim3(Bn * Hh), dim3(256), 0, stream>>>(x, om, dw, conv, part);
    stats_k<<<dim3(1), dim3(128), 0, stream>>>(part, gamma, beta, ss);
    bnrelu_k<<<dim3(Bn * On * HW / 4 / 256), dim3(256), 0, stream>>>(conv, ss, (float*)d_out);
}

// Round 4
// 625.023 us; speedup vs baseline: 3.6989x; 3.6989x over previous
//
#include <hip/hip_runtime.h>
#include <math.h>

#define Hh 128
#define Ww 128
#define HW (Hh*Ww)
#define Bn 4
#define Cn 64
#define On 64
#define CCH 8                 // channels per LDS chunk in dcn_k

// workspace layout (in floats)
#define OM_OFF   0                          // B*27*HW = 1,769,472 floats
#define CONV_OFF (Bn*27*HW)                 // B*64*HW = 4,194,304 floats
#define SS_OFF   (CONV_OFF + Bn*On*HW)      // 128 floats (scale[64], shift[64])
#define PART_OFF (SS_OFF + 128)             // 512 blocks * 128 floats partials

// ---------------------------------------------------------------------------
// Kernel A: offset-predicting 3x3 conv (C=64 -> 27), stride 1, pad 1.
// One thread per pixel, 27 accumulators. NO min-waves clamp (spill hazard).
// ---------------------------------------------------------------------------
__global__ __launch_bounds__(128) void offset_conv_k(
    const float* __restrict__ x, const float* __restrict__ ow,
    const float* __restrict__ ob, float* __restrict__ om)
{
    int bh = blockIdx.x;
    int b = bh >> 7;
    int h = bh & 127;
    int w = threadIdx.x;

    float acc[27];
#pragma unroll
    for (int o = 0; o < 27; ++o) acc[o] = ob[o];

    const float* xb = x + (size_t)b * Cn * HW;
    for (int c = 0; c < Cn; ++c) {
        const float* xp = xb + c * HW;
        float v[9];
#pragma unroll
        for (int ky = 0; ky < 3; ++ky) {
            int yy = h + ky - 1;
            int yc = min(max(yy, 0), Hh - 1);
            bool vy = (yy >= 0) && (yy < Hh);
#pragma unroll
            for (int kx = 0; kx < 3; ++kx) {
                int xx = w + kx - 1;
                int xc = min(max(xx, 0), Ww - 1);
                bool vx = (xx >= 0) && (xx < Ww);
                v[ky * 3 + kx] = (vy && vx) ? xp[yc * Ww + xc] : 0.0f;
            }
        }
        const float* wp = ow + c * 9;   // ow[o*576 + c*9 + t]
#pragma unroll
        for (int o = 0; o < 27; ++o) {
            const float* wo = wp + o * 576;
#pragma unroll
            for (int t = 0; t < 9; ++t) acc[o] += v[t] * wo[t];
        }
    }

    int p = h * Ww + w;
#pragma unroll
    for (int o = 0; o < 27; ++o) {
        float val = acc[o];
        if (o >= 18) val = 1.0f / (1.0f + __expf(-val));  // sigmoid for mask
        om[((size_t)b * 27 + o) * HW + p] = val;
    }
}

// ---------------------------------------------------------------------------
// Kernel B: deformable sampling + DCN conv, LDS-staged.
// Block = 256 threads = one row (b,h), all 64 output channels.
// CRITICAL: no __launch_bounds__ min-waves arg — forcing occupancy made the
// allocator spill acc[32] (R3: 4.9 GB scratch writes, 2.6x regression).
// ---------------------------------------------------------------------------
__global__ __launch_bounds__(256) void dcn_k(
    const float* __restrict__ x, const float* __restrict__ om,
    const float* __restrict__ dw, float* __restrict__ conv,
    float* __restrict__ part)
{
    int b = blockIdx.x >> 7;
    int h = blockIdx.x & 127;
    int t = threadIdx.x;

    __shared__ float sL[CCH * 9 * 128];   // 36 KB

    // ---- prologue: per-(k,px) corner indices & folded weights in registers
    int   pidx[5][4];
    float pfw[5][4];
#pragma unroll
    for (int i = 0; i < 5; ++i) {
        int pid = t + 256 * i;
        bool ok = (pid < 1152);           // only i==4, t>=128 is invalid
        int k  = pid >> 7;
        int px = pid & 127;
        if (ok) {
            int p = h * Ww + px;
            const float* omb = om + (size_t)b * 27 * HW;
            float ox = omb[(size_t)k * HW + p];
            float oy = omb[(size_t)(9 + k) * HW + p];
            float m  = omb[(size_t)(18 + k) * HW + p];  // sigmoided already
            float py  = (float)(h - 1 + (k / 3)) + oy;
            float pxf = (float)(px - 1 + (k % 3)) + ox;
            float y0f = floorf(py), x0f = floorf(pxf);
            int y0 = (int)y0f, x0 = (int)x0f;
            float wy = py - y0f, wx = pxf - x0f;
#pragma unroll
            for (int dy = 0; dy < 2; ++dy) {
#pragma unroll
                for (int dx = 0; dx < 2; ++dx) {
                    int yi = y0 + dy, xi = x0 + dx;
                    bool valid = (yi >= 0) && (yi < Hh) && (xi >= 0) && (xi < Ww);
                    int yc = min(max(yi, 0), Hh - 1);
                    int xc = min(max(xi, 0), Ww - 1);
                    float wgt = (dy ? wy : 1.0f - wy) * (dx ? wx : 1.0f - wx);
                    pfw[i][dy * 2 + dx]  = valid ? (wgt * m) : 0.0f;
                    pidx[i][dy * 2 + dx] = yc * Ww + xc;
                }
            }
        } else {
#pragma unroll
            for (int j = 0; j < 4; ++j) { pfw[i][j] = 0.0f; pidx[i][j] = 0; }
        }
    }

    float acc[32];
#pragma unroll
    for (int j = 0; j < 32; ++j) acc[j] = 0.0f;

    int mypx = t & 127;
    int og   = t >> 7;                    // 0 or 1: outputs og*32 .. og*32+31

    for (int cc = 0; cc < Cn / CCH; ++cc) {
        // ---- sampling phase: fill sL for channels cc*8 .. cc*8+7
        const float* xbase = x + (size_t)(b * Cn + cc * CCH) * HW;
#pragma unroll
        for (int i = 0; i < 5; ++i) {
            int pid = t + 256 * i;
            if (pid < 1152) {
                int k  = pid >> 7;
                int px = pid & 127;
#pragma unroll
                for (int c2 = 0; c2 < CCH; ++c2) {
                    const float* xc = xbase + c2 * HW;
                    float v = pfw[i][0] * xc[pidx[i][0]]
                            + pfw[i][1] * xc[pidx[i][1]]
                            + pfw[i][2] * xc[pidx[i][2]]
                            + pfw[i][3] * xc[pidx[i][3]];
                    sL[(c2 * 9 + k) * 128 + px] = v;
                }
            }
        }
        __syncthreads();

        // ---- einsum phase: acc[j] += sL . w
        const float* wchunk = dw + (size_t)(og * 32) * 576 + cc * CCH * 9;
        for (int c2 = 0; c2 < CCH; ++c2) {
            float s[9];
#pragma unroll
            for (int k = 0; k < 9; ++k) s[k] = sL[(c2 * 9 + k) * 128 + mypx];
#pragma unroll
            for (int j = 0; j < 32; ++j) {
                const float* wo = wchunk + (size_t)j * 576 + c2 * 9;
#pragma unroll
                for (int k = 0; k < 9; ++k) acc[j] += s[k] * wo[k];
            }
        }
        __syncthreads();   // WAR: next chunk overwrites sL
    }

    // ---- store conv output
    float* cv = conv + ((size_t)b * On + og * 32) * HW + h * Ww + mypx;
#pragma unroll
    for (int j = 0; j < 32; ++j) cv[(size_t)j * HW] = acc[j];

    // ---- block stats partials: wave shuffle-reduce, combine via LDS
#pragma unroll
    for (int j = 0; j < 32; ++j) {
        float s1 = acc[j];
        float s2 = acc[j] * acc[j];
#pragma unroll
        for (int off = 32; off > 0; off >>= 1) {
            s1 += __shfl_down(s1, off, 64);
            s2 += __shfl_down(s2, off, 64);
        }
        if ((t & 63) == 0) {
            int wv = t >> 6;                      // wave 0..3 ; og = wv>>1
            sL[0 * 128 + wv * 32 + j] = s1;       // sums
            sL[512 + wv * 32 + j]     = s2;       // sumsq (disjoint region)
        }
    }
    __syncthreads();
    if (t < 128) {
        int stat = t >> 6;         // 0=sum, 1=sumsq
        int o    = t & 63;
        int og2  = o >> 5, j = o & 31;
        float v = sL[stat * 512 + (og2 * 2 + 0) * 32 + j]
                + sL[stat * 512 + (og2 * 2 + 1) * 32 + j];
        part[(size_t)blockIdx.x * 128 + t] = v;
    }
}

// ---------------------------------------------------------------------------
// Kernel C: reduce per-block partials -> BN scale/shift per channel
// ---------------------------------------------------------------------------
__global__ __launch_bounds__(128) void stats_k(
    const float* __restrict__ part, const float* __restrict__ gamma,
    const float* __restrict__ beta, float* __restrict__ ss)
{
    int t = threadIdx.x;           // stat = t>>6, o = t&63
    float a = 0.0f;
    for (int i = 0; i < Bn * Hh; ++i) a += part[(size_t)i * 128 + t];
    __shared__ float tmp[128];
    tmp[t] = a;
    __syncthreads();
    if (t < 64) {
        float n = (float)(Bn * HW);
        float mu = tmp[t] / n;
        float var = tmp[64 + t] / n - mu * mu;
        float sc = gamma[t] * rsqrtf(var + 1e-5f);
        ss[t] = sc;
        ss[64 + t] = beta[t] - mu * sc;
    }
}

// ---------------------------------------------------------------------------
// Kernel D: apply BN + ReLU, vectorized float4
// ---------------------------------------------------------------------------
__global__ __launch_bounds__(256) void bnrelu_k(
    const float* __restrict__ conv, const float* __restrict__ ss,
    float* __restrict__ out)
{
    int i = blockIdx.x * blockDim.x + threadIdx.x;   // float4 index
    int ch = (i >> 12) & 63;                         // HW/4 = 4096 float4/plane
    float sc = ss[ch];
    float sh = ss[64 + ch];
    const float4* cv = (const float4*)conv;
    float4* ov = (float4*)out;
    float4 v = cv[i];
    v.x = fmaxf(v.x * sc + sh, 0.0f);
    v.y = fmaxf(v.y * sc + sh, 0.0f);
    v.z = fmaxf(v.z * sc + sh, 0.0f);
    v.w = fmaxf(v.w * sc + sh, 0.0f);
    ov[i] = v;
}

// ---------------------------------------------------------------------------
extern "C" void kernel_launch(void* const* d_in, const int* in_sizes, int n_in,
                              void* d_out, int out_size, void* d_ws, size_t ws_size,
                              hipStream_t stream)
{
    const float* x     = (const float*)d_in[0];
    const float* ow    = (const float*)d_in[1];
    const float* ob    = (const float*)d_in[2];
    const float* dw    = (const float*)d_in[3];
    // d_in[4] = dcn_b: cancels exactly under BN mean subtraction -> unused
    const float* gamma = (const float*)d_in[5];
    const float* beta  = (const float*)d_in[6];

    float* ws    = (float*)d_ws;
    float* om    = ws + OM_OFF;
    float* conv  = ws + CONV_OFF;
    float* ss    = ws + SS_OFF;
    float* part  = ws + PART_OFF;

    offset_conv_k<<<dim3(Bn * Hh), dim3(128), 0, stream>>>(x, ow, ob, om);
    dcn_k<<<dim3(Bn * Hh), dim3(256), 0, stream>>>(x, om, dw, conv, part);
    stats_k<<<dim3(1), dim3(128), 0, stream>>>(part, gamma, beta, ss);
    bnrelu_k<<<dim3(Bn * On * HW / 4 / 256), dim3(256), 0, stream>>>(conv, ss, (float*)d_out);
}

// Round 5
// 487.036 us; speedup vs baseline: 4.7469x; 1.2833x over previous
//
#include <hip/hip_runtime.h>
#include <math.h>

#define Hh 128
#define Ww 128
#define HW (Hh*Ww)
#define Bn 4
#define Cn 64
#define On 64
#define CCH 8                 // channels per LDS chunk in dcn_k

// workspace layout (in floats)
#define OM_OFF   0                          // B*27*HW = 1,769,472 floats
#define CONV_OFF (Bn*27*HW)                 // B*64*HW = 4,194,304 floats
#define SS_OFF   (CONV_OFF + Bn*On*HW)      // 128 floats (scale[64], shift[64])
#define PART_OFF (SS_OFF + 128)             // 512 blocks * 128 floats partials

// ---------------------------------------------------------------------------
// Kernel A: offset-predicting 3x3 conv (C=64 -> 27), stride 1, pad 1.
// Weight base has no threadIdx dependence -> already scalarizes to s_load.
// ---------------------------------------------------------------------------
__global__ __launch_bounds__(128) void offset_conv_k(
    const float* __restrict__ x, const float* __restrict__ ow,
    const float* __restrict__ ob, float* __restrict__ om)
{
    int bh = blockIdx.x;
    int b = bh >> 7;
    int h = bh & 127;
    int w = threadIdx.x;

    float acc[27];
#pragma unroll
    for (int o = 0; o < 27; ++o) acc[o] = ob[o];

    const float* xb = x + (size_t)b * Cn * HW;
    for (int c = 0; c < Cn; ++c) {
        const float* xp = xb + c * HW;
        float v[9];
#pragma unroll
        for (int ky = 0; ky < 3; ++ky) {
            int yy = h + ky - 1;
            int yc = min(max(yy, 0), Hh - 1);
            bool vy = (yy >= 0) && (yy < Hh);
#pragma unroll
            for (int kx = 0; kx < 3; ++kx) {
                int xx = w + kx - 1;
                int xc = min(max(xx, 0), Ww - 1);
                bool vx = (xx >= 0) && (xx < Ww);
                v[ky * 3 + kx] = (vy && vx) ? xp[yc * Ww + xc] : 0.0f;
            }
        }
        const float* wp = ow + c * 9;   // ow[o*576 + c*9 + t]
#pragma unroll
        for (int o = 0; o < 27; ++o) {
            const float* wo = wp + o * 576;
#pragma unroll
            for (int t = 0; t < 9; ++t) acc[o] += v[t] * wo[t];
        }
    }

    int p = h * Ww + w;
#pragma unroll
    for (int o = 0; o < 27; ++o) {
        float val = acc[o];
        if (o >= 18) val = 1.0f / (1.0f + __expf(-val));  // sigmoid for mask
        om[((size_t)b * 27 + o) * HW + p] = val;
    }
}

// ---------------------------------------------------------------------------
// Kernel B: deformable sampling + DCN conv, LDS-staged.
// Block = 256 threads = one row (b,h), all 64 output channels.
// CRITICAL #1: no __launch_bounds__ min-waves arg (R3: forced occupancy
//   spilled acc[32] -> 4.9 GB scratch traffic, 2.6x regression).
// CRITICAL #2: og must be readfirstlane'd. og = t>>7 is wave-uniform in
//   fact but NOT to LLVM divergence analysis; without this the einsum
//   weight reads compile to 18432 per-lane global_load_dword per thread
//   (R4: VALUBusy 24%, dcn_k 438 us). With an SGPR og the weights become
//   s_load on the scalar pipe and the einsum is pure v_fmac with an SGPR
//   operand.
// ---------------------------------------------------------------------------
__global__ __launch_bounds__(256) void dcn_k(
    const float* __restrict__ x, const float* __restrict__ om,
    const float* __restrict__ dw, float* __restrict__ conv,
    float* __restrict__ part)
{
    int b = blockIdx.x >> 7;
    int h = blockIdx.x & 127;
    int t = threadIdx.x;

    __shared__ float sL[CCH * 9 * 128];   // 36 KB

    // ---- prologue: per-(k,px) corner indices & folded weights in registers
    int   pidx[5][4];
    float pfw[5][4];
#pragma unroll
    for (int i = 0; i < 5; ++i) {
        int pid = t + 256 * i;
        bool ok = (pid < 1152);           // only i==4, t>=128 is invalid
        int k  = pid >> 7;
        int px = pid & 127;
        if (ok) {
            int p = h * Ww + px;
            const float* omb = om + (size_t)b * 27 * HW;
            float ox = omb[(size_t)k * HW + p];
            float oy = omb[(size_t)(9 + k) * HW + p];
            float m  = omb[(size_t)(18 + k) * HW + p];  // sigmoided already
            float py  = (float)(h - 1 + (k / 3)) + oy;
            float pxf = (float)(px - 1 + (k % 3)) + ox;
            float y0f = floorf(py), x0f = floorf(pxf);
            int y0 = (int)y0f, x0 = (int)x0f;
            float wy = py - y0f, wx = pxf - x0f;
#pragma unroll
            for (int dy = 0; dy < 2; ++dy) {
#pragma unroll
                for (int dx = 0; dx < 2; ++dx) {
                    int yi = y0 + dy, xi = x0 + dx;
                    bool valid = (yi >= 0) && (yi < Hh) && (xi >= 0) && (xi < Ww);
                    int yc = min(max(yi, 0), Hh - 1);
                    int xc = min(max(xi, 0), Ww - 1);
                    float wgt = (dy ? wy : 1.0f - wy) * (dx ? wx : 1.0f - wx);
                    pfw[i][dy * 2 + dx]  = valid ? (wgt * m) : 0.0f;
                    pidx[i][dy * 2 + dx] = yc * Ww + xc;
                }
            }
        } else {
#pragma unroll
            for (int j = 0; j < 4; ++j) { pfw[i][j] = 0.0f; pidx[i][j] = 0; }
        }
    }

    float acc[32];
#pragma unroll
    for (int j = 0; j < 32; ++j) acc[j] = 0.0f;

    int mypx = t & 127;
    // wave-uniform output-group index, forced into an SGPR so weight loads
    // scalarize to s_load (see CRITICAL #2 above)
    int og_s = __builtin_amdgcn_readfirstlane(t >> 7);

    for (int cc = 0; cc < Cn / CCH; ++cc) {
        // ---- sampling phase: fill sL for channels cc*8 .. cc*8+7
        const float* xbase = x + (size_t)(b * Cn + cc * CCH) * HW;
#pragma unroll
        for (int i = 0; i < 5; ++i) {
            int pid = t + 256 * i;
            if (pid < 1152) {
                int k  = pid >> 7;
                int px = pid & 127;
#pragma unroll
                for (int c2 = 0; c2 < CCH; ++c2) {
                    const float* xc = xbase + c2 * HW;
                    float v = pfw[i][0] * xc[pidx[i][0]]
                            + pfw[i][1] * xc[pidx[i][1]]
                            + pfw[i][2] * xc[pidx[i][2]]
                            + pfw[i][3] * xc[pidx[i][3]];
                    sL[(c2 * 9 + k) * 128 + px] = v;
                }
            }
        }
        __syncthreads();

        // ---- einsum phase: acc[j] += sL . w   (weights via s_load)
        const float* wchunk = dw + (size_t)(og_s * 32) * 576 + cc * CCH * 9;
        for (int c2 = 0; c2 < CCH; ++c2) {
            float s[9];
#pragma unroll
            for (int k = 0; k < 9; ++k) s[k] = sL[(c2 * 9 + k) * 128 + mypx];
#pragma unroll
            for (int j = 0; j < 32; ++j) {
                const float* wo = wchunk + (size_t)j * 576 + c2 * 9;
#pragma unroll
                for (int k = 0; k < 9; ++k) acc[j] += s[k] * wo[k];
            }
        }
        __syncthreads();   // WAR: next chunk overwrites sL
    }

    // ---- store conv output (base derived from SGPR og_s)
    float* cv = conv + ((size_t)b * On + og_s * 32) * HW + h * Ww + mypx;
#pragma unroll
    for (int j = 0; j < 32; ++j) cv[(size_t)j * HW] = acc[j];

    // ---- block stats partials: wave shuffle-reduce, combine via LDS
#pragma unroll
    for (int j = 0; j < 32; ++j) {
        float s1 = acc[j];
        float s2 = acc[j] * acc[j];
#pragma unroll
        for (int off = 32; off > 0; off >>= 1) {
            s1 += __shfl_down(s1, off, 64);
            s2 += __shfl_down(s2, off, 64);
        }
        if ((t & 63) == 0) {
            int wv = t >> 6;                      // wave 0..3 ; og = wv>>1
            sL[0 * 128 + wv * 32 + j] = s1;       // sums
            sL[512 + wv * 32 + j]     = s2;       // sumsq (disjoint region)
        }
    }
    __syncthreads();
    if (t < 128) {
        int stat = t >> 6;         // 0=sum, 1=sumsq
        int o    = t & 63;
        int og2  = o >> 5, j = o & 31;
        float v = sL[stat * 512 + (og2 * 2 + 0) * 32 + j]
                + sL[stat * 512 + (og2 * 2 + 1) * 32 + j];
        part[(size_t)blockIdx.x * 128 + t] = v;
    }
}

// ---------------------------------------------------------------------------
// Kernel C: reduce per-block partials -> BN scale/shift per channel
// ---------------------------------------------------------------------------
__global__ __launch_bounds__(128) void stats_k(
    const float* __restrict__ part, const float* __restrict__ gamma,
    const float* __restrict__ beta, float* __restrict__ ss)
{
    int t = threadIdx.x;           // stat = t>>6, o = t&63
    float a = 0.0f;
    for (int i = 0; i < Bn * Hh; ++i) a += part[(size_t)i * 128 + t];
    __shared__ float tmp[128];
    tmp[t] = a;
    __syncthreads();
    if (t < 64) {
        float n = (float)(Bn * HW);
        float mu = tmp[t] / n;
        float var = tmp[64 + t] / n - mu * mu;
        float sc = gamma[t] * rsqrtf(var + 1e-5f);
        ss[t] = sc;
        ss[64 + t] = beta[t] - mu * sc;
    }
}

// ---------------------------------------------------------------------------
// Kernel D: apply BN + ReLU, vectorized float4
// ---------------------------------------------------------------------------
__global__ __launch_bounds__(256) void bnrelu_k(
    const float* __restrict__ conv, const float* __restrict__ ss,
    float* __restrict__ out)
{
    int i = blockIdx.x * blockDim.x + threadIdx.x;   // float4 index
    int ch = (i >> 12) & 63;                         // HW/4 = 4096 float4/plane
    float sc = ss[ch];
    float sh = ss[64 + ch];
    const float4* cv = (const float4*)conv;
    float4* ov = (float4*)out;
    float4 v = cv[i];
    v.x = fmaxf(v.x * sc + sh, 0.0f);
    v.y = fmaxf(v.y * sc + sh, 0.0f);
    v.z = fmaxf(v.z * sc + sh, 0.0f);
    v.w = fmaxf(v.w * sc + sh, 0.0f);
    ov[i] = v;
}

// ---------------------------------------------------------------------------
extern "C" void kernel_launch(void* const* d_in, const int* in_sizes, int n_in,
                              void* d_out, int out_size, void* d_ws, size_t ws_size,
                              hipStream_t stream)
{
    const float* x     = (const float*)d_in[0];
    const float* ow    = (const float*)d_in[1];
    const float* ob    = (const float*)d_in[2];
    const float* dw    = (const float*)d_in[3];
    // d_in[4] = dcn_b: cancels exactly under BN mean subtraction -> unused
    const float* gamma = (const float*)d_in[5];
    const float* beta  = (const float*)d_in[6];

    float* ws    = (float*)d_ws;
    float* om    = ws + OM_OFF;
    float* conv  = ws + CONV_OFF;
    float* ss    = ws + SS_OFF;
    float* part  = ws + PART_OFF;

    offset_conv_k<<<dim3(Bn * Hh), dim3(128), 0, stream>>>(x, ow, ob, om);
    dcn_k<<<dim3(Bn * Hh), dim3(256), 0, stream>>>(x, om, dw, conv, part);
    stats_k<<<dim3(1), dim3(128), 0, stream>>>(part, gamma, beta, ss);
    bnrelu_k<<<dim3(Bn * On * HW / 4 / 256), dim3(256), 0, stream>>>(conv, ss, (float*)d_out);
}